// Round 1
// baseline (172.653 us; speedup 1.0000x reference)
//
#include <hip/hip_runtime.h>

// retinex_synthesis, SINGLE-kernel rolling separable blur.
// out = clip((1+ins)*exp(blur(log1p(bg) - log1p(ins))) - 1, 0, 1)
//   (identity: expm1(log1p(ins) + blur(d)) == (1+ins)*exp(blur(d)) - 1,
//    kills the per-output __logf of the old epilogue)
//
// Structure (R6): column strips 64 wide x 128 tall, one block each
// (grid 8*4*48 = 1536 -> 5 resident blocks/CU at 30.2 KB LDS = 20 waves/CU,
// vs 3 blocks/12 waves before: occupancy was the R5 bottleneck —
// VALUBusy 67%, Occupancy 24.6%, HBM only 30%).
// K-loop over 5 chunks of 32 rows:
//   issue epilogue ins loads for this chunk's emit rows (L2-hot, ~1000 cy early)
//   stage chunk k (rows [32k-15, 32k+17), 96 cols) from PREFETCHED registers
//   -> LDS; prefetch chunk k+1 (loads in flight across barriers);
//   barrier; h-blur -> 64-row LDS ring; barrier;
//   emit output rows [32(k-1), 32k) by v-blur from ring + fused epilogue.
// Ring retention window [32k-47, 32k+17) exactly covers emission needs;
// every overwrite/read pair is barrier-separated.
// Emit row addressing is wave-uniform (eg = tid>>6): readfirstlane forces it
// onto the SALU (saves ~2 VALU ops per ring-row read, 38 reads/emit).

constexpr int W_ = 512, H_ = 512, NIMG = 48;
constexpr int TH = 128;             // output rows per block
constexpr int NCH = TH / 32 + 1;    // 5 chunks (last is halo-only fill)
constexpr int SPITCH = 100;  // staging pitch (floats): 96 cols + 4; 25 slots, 25%8==1
constexpr int RPITCH = 68;   // ring pitch (floats): 64 cols + 4; 17 slots, 17%8==1

__device__ constexpr float G[31] = {
    8.8805851e-04f, 1.5861066e-03f, 2.7217699e-03f, 4.4874399e-03f,
    7.1084368e-03f, 1.0818767e-02f, 1.5820117e-02f, 2.2226435e-02f,
    3.0002549e-02f, 3.8911209e-02f, 4.8486352e-02f, 5.8048702e-02f,
    6.6771901e-02f, 7.3794364e-02f, 7.8357552e-02f, 7.9940480e-02f,
    7.8357552e-02f, 7.3794364e-02f, 6.6771901e-02f, 5.8048702e-02f,
    4.8486352e-02f, 3.8911209e-02f, 3.0002549e-02f, 2.2226435e-02f,
    1.5820117e-02f, 1.0818767e-02f, 7.1084368e-03f, 4.4874399e-03f,
    2.7217699e-03f, 1.5861066e-03f, 8.8805851e-04f};

__global__ __launch_bounds__(256, 5) void retinex_roll(const float* __restrict__ bg,
                                                       const float* __restrict__ ins,
                                                       float* __restrict__ out) {
  __shared__ __align__(16) float sd[32 * SPITCH];  // 12,800 B: staged d chunk
  __shared__ __align__(16) float hr[64 * RPITCH];  // 17,408 B: h-blurred ring

  const int tid  = threadIdx.x;
  const int lane = tid & 63;
  const int x0 = blockIdx.x * 64;
  const int y0 = blockIdx.y * TH;
  const size_t base = (size_t)blockIdx.z * (size_t)(H_ * W_);

  // Staging geometry (k-invariant): 768 float4 items = 32 rows x 24 slots.
  int sr[3], sc[3], gx[3]; bool okx[3];
#pragma unroll
  for (int s = 0; s < 3; ++s) {
    const int item = tid + 256 * s;
    sr[s] = item / 24;
    sc[s] = item - 24 * sr[s];
    gx[s] = x0 - 16 + 4 * sc[s];          // float4-aligned; OOB is whole-float4
    okx[s] = (unsigned)gx[s] < (unsigned)W_;
  }
  const int hrow = tid >> 3;              // h-blur: staged row 0..31
  const int hcg  = tid & 7;               // h-blur: col group (8 cols each)
  // emit row-group 0..3 — wave-uniform: force scalar so ring addressing is SALU
  const int eg = __builtin_amdgcn_readfirstlane(tid >> 6);

  // Initial prefetch: chunk 0 = rows y0-15 .. y0+16.
  float4 pb[3], pn[3];
#pragma unroll
  for (int s = 0; s < 3; ++s) {
    const int gy = y0 - 15 + sr[s];
    pb[s] = make_float4(0.f, 0.f, 0.f, 0.f);
    pn[s] = pb[s];
    if (okx[s] && (unsigned)gy < (unsigned)H_) {
      const size_t a = base + (size_t)gy * W_ + gx[s];
      pb[s] = *(const float4*)(bg + a);
      pn[s] = *(const float4*)(ins + a);
    }
  }

#pragma unroll 1
  for (int k = 0; k < NCH; ++k) {
    const int t0 = 32 * (k - 1) + 8 * eg;    // block-relative first emit row (scalar)

    // ---- Issue epilogue ins loads for this chunk's emit rows (consumed ~2
    //      barriers later; L2-hot — staged ~1 chunk ago).
    float insv[8];
    if (k >= 1) {
#pragma unroll
      for (int p = 0; p < 8; ++p)
        insv[p] = ins[base + (size_t)(y0 + t0 + p) * W_ + x0 + lane];
    }

    // ---- Stage chunk k from prefetched registers: d = log1p(bg)-log1p(ins).
#pragma unroll
    for (int s = 0; s < 3; ++s) {
      float4 v;
      v.x = __logf(1.f + pb[s].x) - __logf(1.f + pn[s].x);
      v.y = __logf(1.f + pb[s].y) - __logf(1.f + pn[s].y);
      v.z = __logf(1.f + pb[s].z) - __logf(1.f + pn[s].z);
      v.w = __logf(1.f + pb[s].w) - __logf(1.f + pn[s].w);
      *(float4*)(sd + sr[s] * SPITCH + 4 * sc[s]) = v;   // slot%8=(sr+sc)%8
    }
    // ---- Prefetch chunk k+1 (same registers; stays in flight past barriers).
    if (k < NCH - 1) {
#pragma unroll
      for (int s = 0; s < 3; ++s) {
        const int gy = y0 + 32 * (k + 1) - 15 + sr[s];
        float4 b0 = make_float4(0.f, 0.f, 0.f, 0.f), n0 = b0;
        if (okx[s] && (unsigned)gy < (unsigned)H_) {
          const size_t a = base + (size_t)gy * W_ + gx[s];
          b0 = *(const float4*)(bg + a);
          n0 = *(const float4*)(ins + a);
        }
        pb[s] = b0; pn[s] = n0;
      }
    }
    __syncthreads();   // A: sd ready; also orders prev emit's hr reads vs h-blur writes

    // ---- H-blur staged row `hrow`, output cols 8*hcg..8*hcg+7 -> ring.
    {
      float win[40];
      const float4* p4 = (const float4*)(sd + hrow * SPITCH) + 2 * hcg;
#pragma unroll
      for (int q = 0; q < 10; ++q) {       // slot%8=(hrow+2hcg+q)%8: balanced
        const float4 v = p4[q];
        win[4 * q + 0] = v.x; win[4 * q + 1] = v.y;
        win[4 * q + 2] = v.z; win[4 * q + 3] = v.w;
      }
      float o[8];
#pragma unroll
      for (int e = 0; e < 8; ++e) {
        float a = 0.f;
#pragma unroll
        for (int c = 0; c < 31; ++c) a += G[c] * win[e + 1 + c];
        o[e] = a;
      }
      const int slot = (32 * k - 15 + hrow + 128) & 63;  // logical row 32k-15+hrow
      float* dst = hr + slot * RPITCH + 8 * hcg;
      *(float4*)(dst)     = make_float4(o[0], o[1], o[2], o[3]);
      *(float4*)(dst + 4) = make_float4(o[4], o[5], o[6], o[7]);
    }
    __syncthreads();   // B: ring rows for this chunk ready

    // ---- Emit output rows [32(k-1), 32k): v-blur from ring + epilogue.
    if (k >= 1) {
      float acc[8];
#pragma unroll
      for (int p = 0; p < 8; ++p) acc[p] = 0.f;
#pragma unroll
      for (int j = 0; j < 38; ++j) {
        const int row = (t0 - 15 + j + 128) & 63;        // scalar (SALU)
        const float v = hr[row * RPITCH + lane];         // lane-consecutive
#pragma unroll
        for (int p = 0; p < 8; ++p) {
          const int c = j - p;
          if (c >= 0 && c < 31) acc[p] += G[c] * v;
        }
      }
#pragma unroll
      for (int p = 0; p < 8; ++p) {
        const size_t a = base + (size_t)(y0 + t0 + p) * W_ + x0 + lane;
        // expm1(log1p(ins) + acc) == (1+ins)*exp(acc) - 1
        float r = (1.f + insv[p]) * __expf(acc[p]) - 1.f;
        out[a] = fminf(fmaxf(r, 0.f), 1.f);
      }
    }
  }
}

extern "C" void kernel_launch(void* const* d_in, const int* in_sizes, int n_in,
                              void* d_out, int out_size, void* d_ws, size_t ws_size,
                              hipStream_t stream) {
  const float* bg  = (const float*)d_in[0];
  const float* ins = (const float*)d_in[1];
  float* out = (float*)d_out;
  retinex_roll<<<dim3(8, 4, NIMG), dim3(256), 0, stream>>>(bg, ins, out);
}

// Round 2
// 162.351 us; speedup vs baseline: 1.0635x; 1.0635x over previous
//
#include <hip/hip_runtime.h>

// retinex_synthesis, SINGLE-kernel rolling separable blur.
// out = clip((1+ins)*exp(blur(log1p(bg) - log1p(ins))) - 1, 0, 1)
//   (identity: expm1(log1p(ins) + blur(d)) == (1+ins)*exp(blur(d)) - 1)
//
// Structure (R7 = R5 geometry + safe micro-opts):
// column strips 64 wide x 256 tall, one block each (grid 8*2*48 = 768 =
// exactly 3 blocks/CU, 12 waves/CU). R6's 128-tall/5-blocks-per-CU variant
// REGRESSED (70->88 us): halo overhead +15%, pipeline amortization 1.25x
// vs 1.125x, and early-issued epilogue loads spilled to scratch
// (WRITE_SIZE 49152->55296 KB = +4 KB/block of spill traffic).
// K-loop over 9 chunks of 32 rows:
//   stage chunk k (rows [32k-15, 32k+17), 96 cols) from PREFETCHED registers
//   -> LDS; prefetch chunk k+1 (loads in flight across barriers);
//   barrier; h-blur -> 64-row LDS ring; barrier;
//   emit output rows [32(k-1), 32k) by v-blur from ring + fused epilogue.
// Ring retention window [32k-47, 32k+17) exactly covers emission needs;
// every overwrite/read pair is barrier-separated.
// h-blur is STREAMING (R7): each float4 is accumulated straight into the 8
// output accumulators (no win[40] materialization -> liveness ~12 floats,
// no spill risk, same FMA count/order as R5 -> bitwise identical).
// Emit row addressing is wave-uniform (eg = tid>>6): readfirstlane forces
// the 38 ring-row addresses onto the SALU.

constexpr int W_ = 512, H_ = 512, NIMG = 48;
constexpr int SPITCH = 100;  // staging pitch (floats): 96 cols + 4; 25 slots, 25%8==1
constexpr int RPITCH = 68;   // ring pitch (floats): 64 cols + 4; 17 slots, 17%8==1

__device__ constexpr float G[31] = {
    8.8805851e-04f, 1.5861066e-03f, 2.7217699e-03f, 4.4874399e-03f,
    7.1084368e-03f, 1.0818767e-02f, 1.5820117e-02f, 2.2226435e-02f,
    3.0002549e-02f, 3.8911209e-02f, 4.8486352e-02f, 5.8048702e-02f,
    6.6771901e-02f, 7.3794364e-02f, 7.8357552e-02f, 7.9940480e-02f,
    7.8357552e-02f, 7.3794364e-02f, 6.6771901e-02f, 5.8048702e-02f,
    4.8486352e-02f, 3.8911209e-02f, 3.0002549e-02f, 2.2226435e-02f,
    1.5820117e-02f, 1.0818767e-02f, 7.1084368e-03f, 4.4874399e-03f,
    2.7217699e-03f, 1.5861066e-03f, 8.8805851e-04f};

__global__ __launch_bounds__(256, 3) void retinex_roll(const float* __restrict__ bg,
                                                       const float* __restrict__ ins,
                                                       float* __restrict__ out) {
  __shared__ __align__(16) float sd[32 * SPITCH];  // 12,800 B: staged d chunk
  __shared__ __align__(16) float hr[64 * RPITCH];  // 17,408 B: h-blurred ring

  const int tid  = threadIdx.x;
  const int lane = tid & 63;
  const int x0 = blockIdx.x * 64;
  const int y0 = blockIdx.y * 256;
  const size_t base = (size_t)blockIdx.z * (size_t)(H_ * W_);

  // Staging geometry (k-invariant): 768 float4 items = 32 rows x 24 slots.
  int sr[3], sc[3], gx[3]; bool okx[3];
#pragma unroll
  for (int s = 0; s < 3; ++s) {
    const int item = tid + 256 * s;
    sr[s] = item / 24;
    sc[s] = item - 24 * sr[s];
    gx[s] = x0 - 16 + 4 * sc[s];          // float4-aligned; OOB is whole-float4
    okx[s] = (unsigned)gx[s] < (unsigned)W_;
  }
  const int hrow = tid >> 3;              // h-blur: staged row 0..31
  const int hcg  = tid & 7;               // h-blur: col group (8 cols each)
  // emit row-group 0..3 — wave-uniform: force scalar so ring addressing is SALU
  const int eg = __builtin_amdgcn_readfirstlane(tid >> 6);

  // Initial prefetch: chunk 0 = rows y0-15 .. y0+16.
  float4 pb[3], pn[3];
#pragma unroll
  for (int s = 0; s < 3; ++s) {
    const int gy = y0 - 15 + sr[s];
    pb[s] = make_float4(0.f, 0.f, 0.f, 0.f);
    pn[s] = pb[s];
    if (okx[s] && (unsigned)gy < (unsigned)H_) {
      const size_t a = base + (size_t)gy * W_ + gx[s];
      pb[s] = *(const float4*)(bg + a);
      pn[s] = *(const float4*)(ins + a);
    }
  }

#pragma unroll 1
  for (int k = 0; k < 9; ++k) {
    // ---- Stage chunk k from prefetched registers: d = log1p(bg)-log1p(ins).
#pragma unroll
    for (int s = 0; s < 3; ++s) {
      float4 v;
      v.x = __logf(1.f + pb[s].x) - __logf(1.f + pn[s].x);
      v.y = __logf(1.f + pb[s].y) - __logf(1.f + pn[s].y);
      v.z = __logf(1.f + pb[s].z) - __logf(1.f + pn[s].z);
      v.w = __logf(1.f + pb[s].w) - __logf(1.f + pn[s].w);
      *(float4*)(sd + sr[s] * SPITCH + 4 * sc[s]) = v;   // slot%8=(sr+sc)%8
    }
    // ---- Prefetch chunk k+1 (same registers; stays in flight past barriers).
    if (k < 8) {
#pragma unroll
      for (int s = 0; s < 3; ++s) {
        const int gy = y0 + 32 * (k + 1) - 15 + sr[s];
        float4 b0 = make_float4(0.f, 0.f, 0.f, 0.f), n0 = b0;
        if (okx[s] && (unsigned)gy < (unsigned)H_) {
          const size_t a = base + (size_t)gy * W_ + gx[s];
          b0 = *(const float4*)(bg + a);
          n0 = *(const float4*)(ins + a);
        }
        pb[s] = b0; pn[s] = n0;
      }
    }
    __syncthreads();   // A: sd ready; also orders prev emit's hr reads vs h-blur writes

    // ---- H-blur staged row `hrow`, output cols 8*hcg..8*hcg+7 -> ring.
    //      STREAMING: accumulate each loaded float4 straight into o[8].
    {
      float o[8];
#pragma unroll
      for (int e = 0; e < 8; ++e) o[e] = 0.f;
      const float4* p4 = (const float4*)(sd + hrow * SPITCH) + 2 * hcg;
#pragma unroll
      for (int q = 0; q < 10; ++q) {       // slot%8=(hrow+2hcg+q)%8: balanced
        const float4 v = p4[q];
        const float w[4] = {v.x, v.y, v.z, v.w};
#pragma unroll
        for (int t = 0; t < 4; ++t) {
          const int pos = 4 * q + t;       // window index: sd col 8*hcg + pos
#pragma unroll
          for (int e = 0; e < 8; ++e) {
            const int c = pos - 1 - e;     // compile-time
            if (c >= 0 && c < 31) o[e] += G[c] * w[t];
          }
        }
      }
      const int slot = (32 * k - 15 + hrow + 128) & 63;  // logical row 32k-15+hrow
      float* dst = hr + slot * RPITCH + 8 * hcg;
      *(float4*)(dst)     = make_float4(o[0], o[1], o[2], o[3]);
      *(float4*)(dst + 4) = make_float4(o[4], o[5], o[6], o[7]);
    }
    __syncthreads();   // B: ring rows for this chunk ready

    // ---- Emit output rows [32(k-1), 32k): v-blur from ring + epilogue.
    if (k >= 1) {
      const int t0 = 32 * (k - 1) + 8 * eg;    // block-relative first output row
      float acc[8];
#pragma unroll
      for (int p = 0; p < 8; ++p) acc[p] = 0.f;
#pragma unroll
      for (int j = 0; j < 38; ++j) {
        const int row = (t0 - 15 + j + 128) & 63;        // scalar (SALU)
        const float v = hr[row * RPITCH + lane];         // lane-consecutive
#pragma unroll
        for (int p = 0; p < 8; ++p) {
          const int c = j - p;
          if (c >= 0 && c < 31) acc[p] += G[c] * v;
        }
      }
#pragma unroll
      for (int p = 0; p < 8; ++p) {
        const size_t a = base + (size_t)(y0 + t0 + p) * W_ + x0 + lane;
        const float iv = ins[a];                 // L2-hot (staged ~1 chunk ago)
        // expm1(log1p(ins) + acc) == (1+ins)*exp(acc) - 1
        float r = (1.f + iv) * __expf(acc[p]) - 1.f;
        out[a] = fminf(fmaxf(r, 0.f), 1.f);
      }
    }
  }
}

extern "C" void kernel_launch(void* const* d_in, const int* in_sizes, int n_in,
                              void* d_out, int out_size, void* d_ws, size_t ws_size,
                              hipStream_t stream) {
  const float* bg  = (const float*)d_in[0];
  const float* ins = (const float*)d_in[1];
  float* out = (float*)d_out;
  retinex_roll<<<dim3(8, 2, NIMG), dim3(256), 0, stream>>>(bg, ins, out);
}

// Round 3
// 162.180 us; speedup vs baseline: 1.0646x; 1.0011x over previous
//
#include <hip/hip_runtime.h>

// retinex_synthesis, SINGLE-kernel rolling separable blur.
// out = clip((1+ins)*exp(blur(log1p(bg) - log1p(ins))) - 1, 0, 1)
//
// R8: ONE barrier per chunk (was 2). R7 post-mortem: VALUBusy 58% with 42%
// idle, HBM 34%, occupancy 24% -> barrier/serialization-bound, not VALU-
// bound. Fix: make each inter-barrier phase contain ALL work kinds
// (stage logs + prefetch + h-blur FMA + emit FMA/LDS/exp) with hazards
// resolved by buffer disjointness instead of barriers:
//   - sd double-buffered: stage(k+1)->buf[(k+1)&1] while hblur(k) reads
//     buf[k&1] in the same phase.
//   - ring 96 slots (was 64): emit(k-2) reads logical [32k-79, 32k-18],
//     hblur(k) writes [32k-15, 32k+16] -- disjoint within the 96-row
//     window (span exactly 96). WAR hblur(k+1) vs emit(k-2): logical
//     distance 96 -> same slot, but separated by the phase barrier.
// Schedule per iter k (k=0..9): stage(k+1) | prefetch(k+2) | hblur(k) |
// emit(k-2) ; barrier. Prologue stages chunk 0 + prefetches chunk 1.
// LDS = 2*12.8 + 26.1 = 51.7 KB/block, x3 blocks/CU = 155 KB < 160 ✓.
// Ring row indices are wave-uniform (eg readfirstlane) -> mod-96 via SALU
// conditional subtracts, no runtime %.
// Geometry (proven R5/R7): 64 wide x 256 tall strips, grid 8*2*48 = 768 =
// 3 blocks/CU. Epilogue identity (R7): expm1(log1p(i)+a) == (1+i)*exp(a)-1.

constexpr int W_ = 512, H_ = 512, NIMG = 48;
constexpr int SPITCH = 100;  // staging pitch: 96 cols + 4; 25 slots, 25%8==1
constexpr int RPITCH = 68;   // ring pitch: 64 cols + 4
constexpr int RSLOTS = 96;   // ring rows (logical row mod 96)

__device__ constexpr float G[31] = {
    8.8805851e-04f, 1.5861066e-03f, 2.7217699e-03f, 4.4874399e-03f,
    7.1084368e-03f, 1.0818767e-02f, 1.5820117e-02f, 2.2226435e-02f,
    3.0002549e-02f, 3.8911209e-02f, 4.8486352e-02f, 5.8048702e-02f,
    6.6771901e-02f, 7.3794364e-02f, 7.8357552e-02f, 7.9940480e-02f,
    7.8357552e-02f, 7.3794364e-02f, 6.6771901e-02f, 5.8048702e-02f,
    4.8486352e-02f, 3.8911209e-02f, 3.0002549e-02f, 2.2226435e-02f,
    1.5820117e-02f, 1.0818767e-02f, 7.1084368e-03f, 4.4874399e-03f,
    2.7217699e-03f, 1.5861066e-03f, 8.8805851e-04f};

__global__ __launch_bounds__(256, 3) void retinex_roll(const float* __restrict__ bg,
                                                       const float* __restrict__ ins,
                                                       float* __restrict__ out) {
  __shared__ __align__(16) float sd[2][32 * SPITCH];   // 2 x 12,800 B
  __shared__ __align__(16) float hr[RSLOTS * RPITCH];  // 26,112 B

  const int tid  = threadIdx.x;
  const int lane = tid & 63;
  const int x0 = blockIdx.x * 64;
  const int y0 = blockIdx.y * 256;
  const size_t base = (size_t)blockIdx.z * (size_t)(H_ * W_);

  // Staging geometry (k-invariant): 768 float4 items = 32 rows x 24 slots.
  int sr[3], sc[3], gx[3]; bool okx[3];
#pragma unroll
  for (int s = 0; s < 3; ++s) {
    const int item = tid + 256 * s;
    sr[s] = item / 24;
    sc[s] = item - 24 * sr[s];
    gx[s] = x0 - 16 + 4 * sc[s];          // float4-aligned; OOB is whole-float4
    okx[s] = (unsigned)gx[s] < (unsigned)W_;
  }
  const int hrow = tid >> 3;              // h-blur: staged row 0..31
  const int hcg  = tid & 7;               // h-blur: col group (8 cols each)
  // emit row-group 0..3 — wave-uniform: force scalar so ring addressing is SALU
  const int eg = __builtin_amdgcn_readfirstlane(tid >> 6);

  float4 pb[3], pn[3];

  // ---- Prologue: load chunk 0, stage it into sd[0], prefetch chunk 1.
#pragma unroll
  for (int s = 0; s < 3; ++s) {
    const int gy = y0 - 15 + sr[s];
    pb[s] = make_float4(0.f, 0.f, 0.f, 0.f);
    pn[s] = pb[s];
    if (okx[s] && (unsigned)gy < (unsigned)H_) {
      const size_t a = base + (size_t)gy * W_ + gx[s];
      pb[s] = *(const float4*)(bg + a);
      pn[s] = *(const float4*)(ins + a);
    }
  }
#pragma unroll
  for (int s = 0; s < 3; ++s) {
    float4 v;
    v.x = __logf(1.f + pb[s].x) - __logf(1.f + pn[s].x);
    v.y = __logf(1.f + pb[s].y) - __logf(1.f + pn[s].y);
    v.z = __logf(1.f + pb[s].z) - __logf(1.f + pn[s].z);
    v.w = __logf(1.f + pb[s].w) - __logf(1.f + pn[s].w);
    *(float4*)(&sd[0][0] + sr[s] * SPITCH + 4 * sc[s]) = v;
  }
#pragma unroll
  for (int s = 0; s < 3; ++s) {
    const int gy = y0 + 32 - 15 + sr[s];
    float4 b0 = make_float4(0.f, 0.f, 0.f, 0.f), n0 = b0;
    if (okx[s] && (unsigned)gy < (unsigned)H_) {
      const size_t a = base + (size_t)gy * W_ + gx[s];
      b0 = *(const float4*)(bg + a);
      n0 = *(const float4*)(ins + a);
    }
    pb[s] = b0; pn[s] = n0;
  }
  __syncthreads();

  // ---- Main loop: one barrier per iteration.
#pragma unroll 1
  for (int k = 0; k < 10; ++k) {
    // ---- Stage chunk k+1 from prefetched regs -> sd[(k+1)&1]  (k<=7).
    if (k <= 7) {
      float* sb = &sd[(k + 1) & 1][0];
#pragma unroll
      for (int s = 0; s < 3; ++s) {
        float4 v;
        v.x = __logf(1.f + pb[s].x) - __logf(1.f + pn[s].x);
        v.y = __logf(1.f + pb[s].y) - __logf(1.f + pn[s].y);
        v.z = __logf(1.f + pb[s].z) - __logf(1.f + pn[s].z);
        v.w = __logf(1.f + pb[s].w) - __logf(1.f + pn[s].w);
        *(float4*)(sb + sr[s] * SPITCH + 4 * sc[s]) = v;
      }
    }
    // ---- Prefetch chunk k+2 (loads in flight through rest of phase) (k<=6).
    if (k <= 6) {
#pragma unroll
      for (int s = 0; s < 3; ++s) {
        const int gy = y0 + 32 * (k + 2) - 15 + sr[s];
        float4 b0 = make_float4(0.f, 0.f, 0.f, 0.f), n0 = b0;
        if (okx[s] && (unsigned)gy < (unsigned)H_) {
          const size_t a = base + (size_t)gy * W_ + gx[s];
          b0 = *(const float4*)(bg + a);
          n0 = *(const float4*)(ins + a);
        }
        pb[s] = b0; pn[s] = n0;
      }
    }
    // ---- H-blur chunk k from sd[k&1] -> ring (streaming accumulate) (k<=8).
    if (k <= 8) {
      float o[8];
#pragma unroll
      for (int e = 0; e < 8; ++e) o[e] = 0.f;
      const float4* p4 = (const float4*)(&sd[k & 1][0] + hrow * SPITCH) + 2 * hcg;
#pragma unroll
      for (int q = 0; q < 10; ++q) {
        const float4 v = p4[q];
        const float w[4] = {v.x, v.y, v.z, v.w};
#pragma unroll
        for (int t = 0; t < 4; ++t) {
          const int pos = 4 * q + t;
#pragma unroll
          for (int e = 0; e < 8; ++e) {
            const int c = pos - 1 - e;     // compile-time
            if (c >= 0 && c < 31) o[e] += G[c] * w[t];
          }
        }
      }
      // slot = (32k - 15 + hrow) mod 96, via conditional subtracts.
      int bh = 32 * k + 81;                       // = 32k-15+96 >= 0
      bh -= (bh >= 192) ? 192 : 0;
      bh -= (bh >= 96) ? 96 : 0;                  // (32k+81) mod 96
      int slot = bh + hrow;
      slot -= (slot >= RSLOTS) ? RSLOTS : 0;
      float* dst = hr + slot * RPITCH + 8 * hcg;
      *(float4*)(dst)     = make_float4(o[0], o[1], o[2], o[3]);
      *(float4*)(dst + 4) = make_float4(o[4], o[5], o[6], o[7]);
    }
    // ---- Emit chunk k-2: v-blur from ring + fused epilogue (k>=2).
    if (k >= 2) {
      const int t0 = 32 * (k - 2) + 8 * eg;       // block-relative first row (scalar)
      int be = t0 + 81;                           // (t0 - 15) + 96
      be -= (be >= 192) ? 192 : 0;
      be -= (be >= 96) ? 96 : 0;                  // (t0-15) mod 96
      float acc[8];
#pragma unroll
      for (int p = 0; p < 8; ++p) acc[p] = 0.f;
#pragma unroll
      for (int j = 0; j < 38; ++j) {
        int row = be + j;                          // scalar (SALU)
        row -= (row >= RSLOTS) ? RSLOTS : 0;
        const float v = hr[row * RPITCH + lane];   // lane-consecutive
#pragma unroll
        for (int p = 0; p < 8; ++p) {
          const int c = j - p;
          if (c >= 0 && c < 31) acc[p] += G[c] * v;
        }
      }
#pragma unroll
      for (int p = 0; p < 8; ++p) {
        const size_t a = base + (size_t)(y0 + t0 + p) * W_ + x0 + lane;
        const float iv = ins[a];                 // L2-hot (staged ~2 chunks ago)
        float r = (1.f + iv) * __expf(acc[p]) - 1.f;
        out[a] = fminf(fmaxf(r, 0.f), 1.f);
      }
    }
    __syncthreads();
  }
}

extern "C" void kernel_launch(void* const* d_in, const int* in_sizes, int n_in,
                              void* d_out, int out_size, void* d_ws, size_t ws_size,
                              hipStream_t stream) {
  const float* bg  = (const float*)d_in[0];
  const float* ins = (const float*)d_in[1];
  float* out = (float*)d_out;
  retinex_roll<<<dim3(8, 2, NIMG), dim3(256), 0, stream>>>(bg, ins, out);
}

// Round 4
// 158.587 us; speedup vs baseline: 1.0887x; 1.0227x over previous
//
#include <hip/hip_runtime.h>

// retinex_synthesis, SINGLE-kernel rolling separable blur.
// out = clip((1+ins)*exp(blur(log1p(bg) - log1p(ins))) - 1, 0, 1)
//
// R9 = R7 structure (proven 63us) + LDS-only barriers + early epilogue loads.
// R8 post-mortem: merging to 1 barrier/chunk REGRESSED (63->86us) -- the
// single long phase killed inter-block phase overlap and added 24 VGPR of
// cross-phase liveness. Reverted.
// R9 theory: R7 is latency-bound (VALU 58%, HBM 34%). __syncthreads forces
// s_waitcnt vmcnt(0) before s_barrier -> every chunk eats ~900cy of HBM
// prefetch latency + store drains at barrier A. But all cross-wave hazards
// here are LDS-only (prefetch lands in private VGPRs; stores unordered), so
// barriers need only lgkmcnt(0). Raw s_barrier + explicit lgkmcnt(0) lets
// the prefetch stay in flight across BOTH barriers and the emit phase; the
// vmcnt wait migrates to first use (next chunk's stage). Hazard audit:
//   stage ds_writes -> [lgkm0+bar A] -> hblur ds_reads          OK
//   hblur ds_writes -> [lgkm0+bar B] -> emit ds_reads           OK
//   emit ds_reads complete (own lgkm0 before next bar A) before
//     hblur(k+1) overwrites ring rows (WAR)                     OK
//   pb/pn VGPR deps: compiler-inserted vmcnt before use          OK
// Also: emit's 8 ins loads issued BEFORE the 38-step v-blur loop (same
// phase, no barrier crossing -> no R6-style spill) to hide L2 latency.
//
// Geometry (proven): 64 wide x 256 tall strips, grid 8*2*48 = 768 =
// 3 blocks/CU, 12 waves/CU. 9 chunks of 32 rows:
//   stage chunk k (rows [32k-15,32k+17), 96 cols) from PREFETCHED regs
//   -> LDS; prefetch chunk k+1; [lgkm bar]; h-blur -> 64-row ring;
//   [lgkm bar]; emit rows [32(k-1),32k) by v-blur + fused epilogue.
// h-blur is streaming (R7): float4 accumulated straight into o[8].
// Emit ring addressing wave-uniform via readfirstlane -> SALU.

constexpr int W_ = 512, H_ = 512, NIMG = 48;
constexpr int SPITCH = 100;  // staging pitch: 96 cols + 4; 25 slots, 25%8==1
constexpr int RPITCH = 68;   // ring pitch: 64 cols + 4; 17 slots, 17%8==1

// LDS-only barrier: cross-wave LDS visibility needs lgkmcnt(0) commit, but
// NOT vmcnt drain (that's the __syncthreads tax this kernel avoids).
#define LDS_BARRIER()                                      \
  do {                                                     \
    asm volatile("" ::: "memory");                         \
    asm volatile("s_waitcnt lgkmcnt(0)" ::: "memory");     \
    __builtin_amdgcn_s_barrier();                          \
    asm volatile("" ::: "memory");                         \
  } while (0)

__device__ constexpr float G[31] = {
    8.8805851e-04f, 1.5861066e-03f, 2.7217699e-03f, 4.4874399e-03f,
    7.1084368e-03f, 1.0818767e-02f, 1.5820117e-02f, 2.2226435e-02f,
    3.0002549e-02f, 3.8911209e-02f, 4.8486352e-02f, 5.8048702e-02f,
    6.6771901e-02f, 7.3794364e-02f, 7.8357552e-02f, 7.9940480e-02f,
    7.8357552e-02f, 7.3794364e-02f, 6.6771901e-02f, 5.8048702e-02f,
    4.8486352e-02f, 3.8911209e-02f, 3.0002549e-02f, 2.2226435e-02f,
    1.5820117e-02f, 1.0818767e-02f, 7.1084368e-03f, 4.4874399e-03f,
    2.7217699e-03f, 1.5861066e-03f, 8.8805851e-04f};

__global__ __launch_bounds__(256, 3) void retinex_roll(const float* __restrict__ bg,
                                                       const float* __restrict__ ins,
                                                       float* __restrict__ out) {
  __shared__ __align__(16) float sd[32 * SPITCH];  // 12,800 B: staged d chunk
  __shared__ __align__(16) float hr[64 * RPITCH];  // 17,408 B: h-blurred ring

  const int tid  = threadIdx.x;
  const int lane = tid & 63;
  const int x0 = blockIdx.x * 64;
  const int y0 = blockIdx.y * 256;
  const size_t base = (size_t)blockIdx.z * (size_t)(H_ * W_);

  // Staging geometry (k-invariant): 768 float4 items = 32 rows x 24 slots.
  int sr[3], sc[3], gx[3]; bool okx[3];
#pragma unroll
  for (int s = 0; s < 3; ++s) {
    const int item = tid + 256 * s;
    sr[s] = item / 24;
    sc[s] = item - 24 * sr[s];
    gx[s] = x0 - 16 + 4 * sc[s];          // float4-aligned; OOB is whole-float4
    okx[s] = (unsigned)gx[s] < (unsigned)W_;
  }
  const int hrow = tid >> 3;              // h-blur: staged row 0..31
  const int hcg  = tid & 7;               // h-blur: col group (8 cols each)
  // emit row-group 0..3 — wave-uniform: force scalar so ring addressing is SALU
  const int eg = __builtin_amdgcn_readfirstlane(tid >> 6);

  // Initial prefetch: chunk 0 = rows y0-15 .. y0+16.
  float4 pb[3], pn[3];
#pragma unroll
  for (int s = 0; s < 3; ++s) {
    const int gy = y0 - 15 + sr[s];
    pb[s] = make_float4(0.f, 0.f, 0.f, 0.f);
    pn[s] = pb[s];
    if (okx[s] && (unsigned)gy < (unsigned)H_) {
      const size_t a = base + (size_t)gy * W_ + gx[s];
      pb[s] = *(const float4*)(bg + a);
      pn[s] = *(const float4*)(ins + a);
    }
  }

#pragma unroll 1
  for (int k = 0; k < 9; ++k) {
    // ---- Stage chunk k from prefetched registers: d = log1p(bg)-log1p(ins).
#pragma unroll
    for (int s = 0; s < 3; ++s) {
      float4 v;
      v.x = __logf(1.f + pb[s].x) - __logf(1.f + pn[s].x);
      v.y = __logf(1.f + pb[s].y) - __logf(1.f + pn[s].y);
      v.z = __logf(1.f + pb[s].z) - __logf(1.f + pn[s].z);
      v.w = __logf(1.f + pb[s].w) - __logf(1.f + pn[s].w);
      *(float4*)(sd + sr[s] * SPITCH + 4 * sc[s]) = v;   // slot%8=(sr+sc)%8
    }
    // ---- Prefetch chunk k+1; loads stay in flight until next iteration's
    //      stage (vmcnt wait at first USE, not at the barriers).
    if (k < 8) {
#pragma unroll
      for (int s = 0; s < 3; ++s) {
        const int gy = y0 + 32 * (k + 1) - 15 + sr[s];
        float4 b0 = make_float4(0.f, 0.f, 0.f, 0.f), n0 = b0;
        if (okx[s] && (unsigned)gy < (unsigned)H_) {
          const size_t a = base + (size_t)gy * W_ + gx[s];
          b0 = *(const float4*)(bg + a);
          n0 = *(const float4*)(ins + a);
        }
        pb[s] = b0; pn[s] = n0;
      }
    }
    LDS_BARRIER();   // A: sd ready; also orders prev emit's hr reads vs h-blur writes

    // ---- H-blur staged row `hrow`, output cols 8*hcg..8*hcg+7 -> ring.
    //      STREAMING: accumulate each loaded float4 straight into o[8].
    {
      float o[8];
#pragma unroll
      for (int e = 0; e < 8; ++e) o[e] = 0.f;
      const float4* p4 = (const float4*)(sd + hrow * SPITCH) + 2 * hcg;
#pragma unroll
      for (int q = 0; q < 10; ++q) {       // slot%8=(hrow+2hcg+q)%8: balanced
        const float4 v = p4[q];
        const float w[4] = {v.x, v.y, v.z, v.w};
#pragma unroll
        for (int t = 0; t < 4; ++t) {
          const int pos = 4 * q + t;       // window index: sd col 8*hcg + pos
#pragma unroll
          for (int e = 0; e < 8; ++e) {
            const int c = pos - 1 - e;     // compile-time
            if (c >= 0 && c < 31) o[e] += G[c] * w[t];
          }
        }
      }
      const int slot = (32 * k - 15 + hrow + 128) & 63;  // logical row 32k-15+hrow
      float* dst = hr + slot * RPITCH + 8 * hcg;
      *(float4*)(dst)     = make_float4(o[0], o[1], o[2], o[3]);
      *(float4*)(dst + 4) = make_float4(o[4], o[5], o[6], o[7]);
    }
    LDS_BARRIER();   // B: ring rows for this chunk ready

    // ---- Emit output rows [32(k-1), 32k): v-blur from ring + epilogue.
    if (k >= 1) {
      const int t0 = 32 * (k - 1) + 8 * eg;    // block-relative first output row
      // Issue epilogue ins loads NOW (L2-hot, staged ~1 chunk ago); their
      // latency hides under the 38-step v-blur. Same phase -> no spill.
      float insv[8];
#pragma unroll
      for (int p = 0; p < 8; ++p)
        insv[p] = ins[base + (size_t)(y0 + t0 + p) * W_ + x0 + lane];
      float acc[8];
#pragma unroll
      for (int p = 0; p < 8; ++p) acc[p] = 0.f;
#pragma unroll
      for (int j = 0; j < 38; ++j) {
        const int row = (t0 - 15 + j + 128) & 63;        // scalar (SALU)
        const float v = hr[row * RPITCH + lane];         // lane-consecutive
#pragma unroll
        for (int p = 0; p < 8; ++p) {
          const int c = j - p;
          if (c >= 0 && c < 31) acc[p] += G[c] * v;
        }
      }
#pragma unroll
      for (int p = 0; p < 8; ++p) {
        const size_t a = base + (size_t)(y0 + t0 + p) * W_ + x0 + lane;
        // expm1(log1p(ins) + acc) == (1+ins)*exp(acc) - 1
        float r = (1.f + insv[p]) * __expf(acc[p]) - 1.f;
        out[a] = fminf(fmaxf(r, 0.f), 1.f);
      }
    }
  }
}

extern "C" void kernel_launch(void* const* d_in, const int* in_sizes, int n_in,
                              void* d_out, int out_size, void* d_ws, size_t ws_size,
                              hipStream_t stream) {
  const float* bg  = (const float*)d_in[0];
  const float* ins = (const float*)d_in[1];
  float* out = (float*)d_out;
  retinex_roll<<<dim3(8, 2, NIMG), dim3(256), 0, stream>>>(bg, ins, out);
}